// Round 11
// baseline (705.837 us; speedup 1.0000x reference)
//
#include <hip/hip_runtime.h>

typedef unsigned int uint;
typedef unsigned short ushort_t;
typedef unsigned long long u64;
typedef __attribute__((ext_vector_type(4))) float f32x4;
typedef __attribute__((ext_vector_type(8))) __bf16 bf16x8;
typedef __attribute__((ext_vector_type(8))) unsigned short us8;

#define BATCH 65536
#define VEC 512
#define K 1024
#define GAMMA 0.99f
#define EPS 1e-05f
#define SEG 64
#define MARGIN 0.75f

// GEMM geometry: 128x256 tile, 8 waves (2M x 4N), per-wave 64x64, BK=32
#define NKT (VEC / 32)      // 16 K-tiles

// round-to-nearest-even f32 -> bf16
__device__ __forceinline__ ushort_t rtn(float f) {
    uint u = __float_as_uint(f);
    return (ushort_t)((u + 0x7FFFu + ((u >> 16) & 1u)) >> 16);
}

__device__ __forceinline__ void gl16(const void* g, void* l) {
    __builtin_amdgcn_global_load_lds(
        (const __attribute__((address_space(1))) unsigned int*)g,
        (__attribute__((address_space(3))) unsigned int*)l, 16, 0, 0);
}

__device__ __forceinline__ float dec_key(uint e) {
    uint b = (e & 0x80000000u) ? (e & 0x7FFFFFFFu) : ~e;
    return __uint_as_float(b);
}

// ---- pack w (bf16-rtn granules) + wT (f32 transpose) + w2 partials + inits ----
// grid 64 blocks (gx 4 x ks 16) x 256 thr
__global__ void k_pack_w(const float* __restrict__ w, us8* __restrict__ wpk,
                         float* __restrict__ wT, float* __restrict__ w2p,
                         int* __restrict__ cc /* counts|cursor|listcnt */) {
    __shared__ float lds[32][257];
    const int g = blockIdx.x;
    const int gx = g >> 4, ks = g & 15;
    const int t = threadIdx.x;

#pragma unroll
    for (int r = 0; r < 32; ++r)
        lds[r][t] = w[(size_t)(ks * 32 + r) * K + gx * 256 + t];
    __syncthreads();

    // w2 partial for this ks-slice
    float s = 0.f;
#pragma unroll
    for (int r = 0; r < 32; ++r) { float f = lds[r][t]; s += f * f; }
    w2p[ks * K + gx * 256 + t] = s;

    // bf16 granules: [ct 16][lane 64], lane=(col&15)|(k8<<4), elems k=k8*8+j
#pragma unroll
    for (int i = 0; i < 4; ++i) {
        const int o = i * 256 + t;
        const int lane = o & 63, ct = o >> 6;
        const int cl = ct * 16 + (lane & 15);
        const int r0 = (lane >> 4) * 8;
        us8 v;
#pragma unroll
        for (int j = 0; j < 8; ++j) v[j] = rtn(lds[r0 + j][cl]);
        wpk[(size_t)g * 1024 + o] = v;
    }

    // wT: (K, VEC) f32 transpose for coalesced per-col reads in recheck
#pragma unroll
    for (int rr = 0; rr < 8; ++rr) {
        f32x4 v = {lds[rr * 4 + 0][t], lds[rr * 4 + 1][t], lds[rr * 4 + 2][t], lds[rr * 4 + 3][t]};
        *(f32x4*)&wT[(size_t)(gx * 256 + t) * VEC + ks * 32 + rr * 4] = v;
    }

    if (g < 8) cc[g * 256 + t] = 0;
    if (g == 8 && t == 0) cc[2048] = 0;
}

// ---- main: 128x256 single-bf16 MFMA distance GEMM, top-2 per row per slot ----
// 2048 blocks x 512 thr; 3 blocks/CU (48KB LDS, 64 VGPR).
// Counted-vmcnt pipeline: next-tile B gl16 stays in flight across barriers.
__launch_bounds__(512, 6)
__global__ void k_gemm(const float* __restrict__ x, const us8* __restrict__ wpk,
                       const float* __restrict__ w2p,
                       u64* __restrict__ keysA, u64* __restrict__ keysB) {
    __shared__ us8 a_lds[2][512];    // 128 rows x 32k bf16, 8KB/buf
    __shared__ us8 b_lds[2][1024];   // 256 cols x 32k bf16, 16KB/buf

    const int blk = blockIdx.x;
    // XCD-chunked bijection (2048 % 8 == 0): XCD c owns gy [c*64, c*64+64),
    // the 4 gx of each gy adjacent -> A-tile L2 reuse.
    const int gy = (blk & 7) * 64 + ((blk >> 3) >> 2);
    const int gx = (blk >> 3) & 3;
    const int t = threadIdx.x;
    const int lane = t & 63;
    const int wv = t >> 6;
    const int wm = wv >> 2;      // 0..1 (64 rows)
    const int wn = wv & 3;       // 0..3 (64 cols)

    const us8* bsrc = wpk + (size_t)gx * (NKT * 1024);

    // A staging: thread t owns granule t: slab=t>>6, al=t&63
    const int al = t & 63;
    const float* xp = x + (size_t)(gy * 128 + (t >> 6) * 16 + (al & 15)) * VEC + (al >> 4) * 8;
    f32x4 av0, av1;
    auto aload = [&](int kt) {
        const float* p = xp + kt * 32;
        av0 = *(const f32x4*)p;
        av1 = *(const f32x4*)(p + 4);
    };
    auto awrite = [&](int buf) {
        us8 h;
#pragma unroll
        for (int j = 0; j < 4; ++j) { h[j] = rtn(av0[j]); h[4 + j] = rtn(av1[j]); }
        a_lds[buf][t] = h;
    };
    auto bstage = [&](int buf, int kt) {
        const us8* sb = bsrc + (size_t)kt * 1024;
        gl16(sb + t, &b_lds[buf][t]);
        gl16(sb + 512 + t, &b_lds[buf][512 + t]);
    };

    f32x4 acc[4][4];
#pragma unroll
    for (int i = 0; i < 4; ++i)
#pragma unroll
        for (int j = 0; j < 4; ++j) acc[i][j] = (f32x4){0.f, 0.f, 0.f, 0.f};

    // prologue: tile 0. aload->awrite (compiler inserts its own precise vmcnt
    // for the av dependency); gl16(0) stays in flight; lgkm drained before B1.
    aload(0);
    bstage(0, 0);
    awrite(0);
    asm volatile("s_waitcnt lgkmcnt(0)" ::: "memory");

    for (int tk = 0; tk < NKT; ++tk) {
        const int buf = tk & 1;
        const bool nx = (tk + 1 < NKT);
        if (nx) {
            aload(tk + 1);              // 2 vmem (vgpr dest)
            bstage(buf ^ 1, tk + 1);    // 2 vmem (lds dest)
            // drain gl16(tk) [oldest]; leave aload(tk+1)+gl16(tk+1) in flight
            asm volatile("s_waitcnt vmcnt(4)" ::: "memory");
        } else {
            asm volatile("s_waitcnt vmcnt(0)" ::: "memory");
        }
        __builtin_amdgcn_s_barrier();   // B1: all threads' tile-tk staging visible

        bf16x8 bh[4];
#pragma unroll
        for (int ct = 0; ct < 4; ++ct)
            bh[ct] = __builtin_bit_cast(bf16x8, b_lds[buf][(wn * 4 + ct) * 64 + lane]);
#pragma unroll
        for (int rt = 0; rt < 4; ++rt) {
            bf16x8 ah = __builtin_bit_cast(bf16x8, a_lds[buf][(wm * 4 + rt) * 64 + lane]);
#pragma unroll
            for (int ct = 0; ct < 4; ++ct)
                acc[rt][ct] = __builtin_amdgcn_mfma_f32_16x16x32_bf16(ah, bh[ct], acc[rt][ct], 0, 0, 0);
        }

        if (nx) awrite(buf ^ 1);        // compiler inserts vmcnt for av regs
        asm volatile("s_waitcnt lgkmcnt(0)" ::: "memory");
        __builtin_amdgcn_s_barrier();   // B2: awrite visible; WAR guard
    }

    // epilogue: dist = w2 - 2*dot; per-row TOP-2 over this wave's 64 cols;
    // plain store to slot (gx*4+wn) -- no atomics, deterministic.
    const int col_base = gx * 256 + wn * 64;
    float w2c[4];
#pragma unroll
    for (int ct = 0; ct < 4; ++ct) {
        const int col = col_base + ct * 16 + (lane & 15);
        float s = 0.f;
#pragma unroll
        for (int p = 0; p < 16; ++p) s += w2p[p * K + col];
        w2c[ct] = s;
    }
    const int slot = gx * 4 + wn;

#pragma unroll
    for (int rt = 0; rt < 4; ++rt) {
#pragma unroll
        for (int reg = 0; reg < 4; ++reg) {
            u64 k1 = ~0ull, k2 = ~0ull;
#pragma unroll
            for (int ct = 0; ct < 4; ++ct) {
                float dist = w2c[ct] - 2.0f * acc[rt][ct][reg];
                uint su = __float_as_uint(dist);
                su = (su & 0x80000000u) ? ~su : (su | 0x80000000u);
                const u64 key = ((u64)su << 32) | (uint)(col_base + ct * 16 + (lane & 15));
                if (key < k1) { k2 = k1; k1 = key; }
                else if (key < k2) { k2 = key; }
            }
#pragma unroll
            for (int m = 1; m < 16; m <<= 1) {
                u64 o1 = __shfl_xor((unsigned long long)k1, m);
                u64 o2 = __shfl_xor((unsigned long long)k2, m);
                u64 lo = k1 < o1 ? k1 : o1;
                u64 hi = k1 < o1 ? o1 : k1;
                u64 mn2 = k2 < o2 ? k2 : o2;
                k1 = lo;
                k2 = hi < mn2 ? hi : mn2;
            }
            if ((lane & 15) == 0) {
                const int row = gy * 128 + wm * 64 + rt * 16 + (lane >> 4) * 4 + reg;
                keysA[(size_t)slot * BATCH + row] = k1;
                keysB[(size_t)slot * BATCH + row] = k2;
            }
        }
    }
}

// ---- verify: merge 16 slots/row -> global top-2; margin test; hist; list ----
__global__ void k_verify(const u64* __restrict__ keysA, const u64* __restrict__ keysB,
                         int* __restrict__ am, int* __restrict__ counts,
                         u64* __restrict__ list, int* __restrict__ listcnt,
                         float* __restrict__ esum) {
    const int r = blockIdx.x * 256 + threadIdx.x;
    f32x4 z = {0.f, 0.f, 0.f, 0.f};
    ((f32x4*)esum)[r * 2] = z;
    ((f32x4*)esum)[r * 2 + 1] = z;

    u64 m1 = ~0ull, s = ~0ull;
    int i1 = 0;
#pragma unroll
    for (int i = 0; i < 16; ++i) {
        u64 a = keysA[(size_t)i * BATCH + r];
        if (a < m1) { s = m1; m1 = a; i1 = i; }
        else if (a < s) s = a;
    }
    u64 b = keysB[(size_t)i1 * BATCH + r];
    u64 m2 = s < b ? s : b;

    const float d1 = dec_key((uint)(m1 >> 32));
    const float d2 = dec_key((uint)(m2 >> 32));
    const int c1 = (int)(uint)m1 & 1023;
    const int c2 = (int)(uint)m2 & 1023;

    if (d2 - d1 > MARGIN) {
        am[r] = c1;
        atomicAdd(&counts[c1], 1);
    } else {
        int p = atomicAdd(listcnt, 1);
        list[p] = ((u64)(uint)r << 32) | ((uint)c1 << 10) | (uint)c2;
    }
}

// ---- recheck: exact f32 distance for the 2 candidates of marginal rows ----
__launch_bounds__(256)
__global__ void k_recheck(const float* __restrict__ x, const float* __restrict__ wT,
                          const float* __restrict__ w2p, const u64* __restrict__ list,
                          const int* __restrict__ listcnt, int* __restrict__ am,
                          int* __restrict__ counts) {
    const int gwid = (blockIdx.x * 256 + threadIdx.x) >> 6;   // 1024 waves
    const int lane = threadIdx.x & 63;
    const int n = *listcnt;
    for (int idx = gwid; idx < n; idx += 1024) {
        const u64 e = list[idx];
        const int r = (int)(e >> 32);
        const int c1 = (int)((e >> 10) & 1023);
        const int c2 = (int)(e & 1023);
        const f32x4 x0 = *(const f32x4*)&x[(size_t)r * VEC + lane * 8];
        const f32x4 x1 = *(const f32x4*)&x[(size_t)r * VEC + lane * 8 + 4];
        float d[2];
        const int cc2[2] = {c1, c2};
#pragma unroll
        for (int j = 0; j < 2; ++j) {
            const int c = cc2[j];
            const f32x4 w0 = *(const f32x4*)&wT[(size_t)c * VEC + lane * 8];
            const f32x4 w1 = *(const f32x4*)&wT[(size_t)c * VEC + lane * 8 + 4];
            float p = x0[0] * w0[0] + x0[1] * w0[1] + x0[2] * w0[2] + x0[3] * w0[3]
                    + x1[0] * w1[0] + x1[1] * w1[1] + x1[2] * w1[2] + x1[3] * w1[3];
#pragma unroll
            for (int m = 1; m < 64; m <<= 1) p += __shfl_xor(p, m);
            float w2 = 0.f;
#pragma unroll
            for (int q = 0; q < 16; ++q) w2 += w2p[q * K + c];
            d[j] = w2 - 2.0f * p;
        }
        const int win = (d[0] < d[1] || (d[0] == d[1] && c1 < c2)) ? c1 : c2;
        if (lane == 0) {
            am[r] = win;
            atomicAdd(&counts[win], 1);
        }
    }
}

// ---- scan of counts -> offsets; EMA cluster sizes -> cs (wave-shuffle) ----
__global__ void k_scan(const int* __restrict__ counts,
                       const float* __restrict__ cluster_size,
                       int* __restrict__ offsets, float* __restrict__ cs) {
    __shared__ int wsum[16];
    __shared__ float fw[16];
    const int t = threadIdx.x;           // 0..1023
    const int lane = t & 63, wid = t >> 6;
    const int c = counts[t];

    int s = c;
#pragma unroll
    for (int d = 1; d < 64; d <<= 1) {
        int o = __shfl_up(s, d);
        if (lane >= d) s += o;
    }
    float ncs = GAMMA * cluster_size[t] + (1.0f - GAMMA) * ((c == 0) ? 1.0f : (float)c);
    float fs = ncs;
#pragma unroll
    for (int d = 32; d > 0; d >>= 1) fs += __shfl_xor(fs, d);

    if (lane == 63) wsum[wid] = s;
    if (lane == 0) fw[wid] = fs;
    __syncthreads();
    if (wid == 0 && lane < 16) {
        int v = wsum[lane];
#pragma unroll
        for (int d = 1; d < 16; d <<= 1) {
            int o = __shfl_up(v, d);
            if (lane >= d) v += o;
        }
        wsum[lane] = v;
    }
    __syncthreads();
    const int base = wid ? wsum[wid - 1] : 0;
    offsets[t] = base + s - c;

    float n = 0.f;
#pragma unroll
    for (int i = 0; i < 16; ++i) n += fw[i];
    cs[t] = (ncs + EPS) / (n + (float)K * EPS) * n;
}

// ---- counting-sort scatter ----
__global__ void k_scatter(const int* __restrict__ am, const int* __restrict__ offsets,
                          int* __restrict__ cursor, int* __restrict__ sorted,
                          int* __restrict__ sortedk) {
    const int b = blockIdx.x * blockDim.x + threadIdx.x;
    const int k = am[b];
    const int pos = atomicAdd(&cursor[k], 1);
    sorted[offsets[k] + pos] = b;
    sortedk[offsets[k] + pos] = k;
}

// ---- balanced segmented reduction: 64 sorted rows per block ----
__launch_bounds__(512)
__global__ void k_segred(const float* __restrict__ x, const int* __restrict__ sorted,
                         const int* __restrict__ sortedk, float* __restrict__ esum) {
    __shared__ int srow[SEG];
    __shared__ int skid[SEG];
    const int b = blockIdx.x;
    const int t = threadIdx.x;
    if (t < SEG) {
        srow[t] = sorted[b * SEG + t];
        skid[t] = sortedk[b * SEG + t];
    }
    __syncthreads();

    float a = 0.f;
    int cur = skid[0];
#pragma unroll 8
    for (int i = 0; i < SEG; ++i) {
        const int k = skid[i];
        if (k != cur) {
            atomicAdd(&esum[(size_t)cur * VEC + t], a);
            a = 0.f;
            cur = k;
        }
        a += x[(size_t)srow[i] * VEC + t];
    }
    atomicAdd(&esum[(size_t)cur * VEC + t], a);
}

// ---- finalize: transpose esum (K,VEC)->(VEC,K), EMA + normalize ----
__launch_bounds__(256)
__global__ void k_finalize(const float* __restrict__ esum, const float* __restrict__ embed_avg,
                           const float* __restrict__ cs, float* __restrict__ out) {
    __shared__ float tile[64][65];
    const int k0 = blockIdx.x * 64;
    const int v0 = blockIdx.y * 64;
    const int c = threadIdx.x & 63;
    const int r0 = threadIdx.x >> 6;
#pragma unroll
    for (int j = 0; j < 16; ++j) {
        const int r = r0 + j * 4;
        tile[r][c] = esum[(size_t)(k0 + r) * VEC + v0 + c];
    }
    __syncthreads();
    const float csk = cs[k0 + c];
#pragma unroll
    for (int j = 0; j < 16; ++j) {
        const int r = r0 + j * 4;
        const size_t o = (size_t)(v0 + r) * K + k0 + c;
        out[o] = (GAMMA * embed_avg[o] + (1.0f - GAMMA) * tile[c][r]) / csk;
    }
}

extern "C" void kernel_launch(void* const* d_in, const int* in_sizes, int n_in,
                              void* d_out, int out_size, void* d_ws, size_t ws_size,
                              hipStream_t stream) {
    const float* x            = (const float*)d_in[0];   // (BATCH, VEC)
    const float* w            = (const float*)d_in[1];   // (VEC, K)
    const float* cluster_size = (const float*)d_in[2];   // (K,)
    const float* embed_avg    = (const float*)d_in[3];   // (VEC, K)
    float* out = (float*)d_out;                          // (VEC, K)

    // ws layout (~23 MB)
    u64*   keysA   = (u64*)d_ws;                          // 16 x BATCH
    u64*   keysB   = keysA + (size_t)16 * BATCH;          // 16 x BATCH
    int*   am      = (int*)(keysB + (size_t)16 * BATCH);  // BATCH
    u64*   list    = (u64*)(am + BATCH);                  // BATCH
    float* w2p     = (float*)(list + BATCH);              // 16 x K
    float* cs      = w2p + 16 * K;                        // K
    int*   cc      = (int*)(cs + K);                      // counts K | cursor K | listcnt (+pad)
    int*   counts  = cc;
    int*   cursor  = cc + K;
    int*   listcnt = cc + 2 * K;
    int*   offsets = cc + 2 * K + 64;                     // K
    int*   sorted  = offsets + K;                         // BATCH
    int*   sortedk = sorted + BATCH;                      // BATCH
    float* esum    = (float*)(sortedk + BATCH);           // (K, VEC), 2 MB
    us8*   wpk     = (us8*)(esum + (size_t)K * VEC);      // 1 MB
    float* wT      = (float*)(wpk + (size_t)64 * 1024);   // (K, VEC), 2 MB

    k_pack_w<<<64, 256, 0, stream>>>(w, wpk, wT, w2p, cc);
    k_gemm<<<2048, 512, 0, stream>>>(x, wpk, w2p, keysA, keysB);
    k_verify<<<BATCH / 256, 256, 0, stream>>>(keysA, keysB, am, counts, list, listcnt, esum);
    k_recheck<<<256, 256, 0, stream>>>(x, wT, w2p, list, listcnt, am, counts);
    k_scan<<<1, K, 0, stream>>>(counts, cluster_size, offsets, cs);
    k_scatter<<<BATCH / 256, 256, 0, stream>>>(am, offsets, cursor, sorted, sortedk);
    k_segred<<<BATCH / SEG, 512, 0, stream>>>(x, sorted, sortedk, esum);
    k_finalize<<<dim3(K / 64, VEC / 64), 256, 0, stream>>>(esum, embed_avg, cs, out);
}

// Round 12
// 393.783 us; speedup vs baseline: 1.7925x; 1.7925x over previous
//
#include <hip/hip_runtime.h>

typedef unsigned int uint;
typedef unsigned short ushort_t;
typedef unsigned long long u64;
typedef __attribute__((ext_vector_type(4))) float f32x4;
typedef __attribute__((ext_vector_type(8))) __bf16 bf16x8;
typedef __attribute__((ext_vector_type(8))) unsigned short us8;

#define BATCH 65536
#define VEC 512
#define K 1024
#define GAMMA 0.99f
#define EPS 1e-05f
#define SEG 64
#define MARGIN 0.75f

// GEMM geometry: 128x256 tile, 8 waves (2M x 4N), per-wave 64x64, BK=32
#define NKT (VEC / 32)      // 16 K-tiles

// round-to-nearest-even f32 -> bf16
__device__ __forceinline__ ushort_t rtn(float f) {
    uint u = __float_as_uint(f);
    return (ushort_t)((u + 0x7FFFu + ((u >> 16) & 1u)) >> 16);
}

__device__ __forceinline__ void gl16(const void* g, void* l) {
    __builtin_amdgcn_global_load_lds(
        (const __attribute__((address_space(1))) unsigned int*)g,
        (__attribute__((address_space(3))) unsigned int*)l, 16, 0, 0);
}

__device__ __forceinline__ float dec_key(uint e) {
    uint b = (e & 0x80000000u) ? (e & 0x7FFFFFFFu) : ~e;
    return __uint_as_float(b);
}

// ---- pack w (bf16-rtn granules) + wT (f32 transpose) + w2 partials + inits ----
// grid 64 blocks (gx 4 x ks 16) x 256 thr
__global__ void k_pack_w(const float* __restrict__ w, us8* __restrict__ wpk,
                         float* __restrict__ wT, float* __restrict__ w2p,
                         int* __restrict__ cc /* counts|cursor|listcnt */) {
    __shared__ float lds[32][257];
    const int g = blockIdx.x;
    const int gx = g >> 4, ks = g & 15;
    const int t = threadIdx.x;

#pragma unroll
    for (int r = 0; r < 32; ++r)
        lds[r][t] = w[(size_t)(ks * 32 + r) * K + gx * 256 + t];
    __syncthreads();

    // w2 partial for this ks-slice
    float s = 0.f;
#pragma unroll
    for (int r = 0; r < 32; ++r) { float f = lds[r][t]; s += f * f; }
    w2p[ks * K + gx * 256 + t] = s;

    // bf16 granules: [ct 16][lane 64], lane=(col&15)|(k8<<4), elems k=k8*8+j
#pragma unroll
    for (int i = 0; i < 4; ++i) {
        const int o = i * 256 + t;
        const int lane = o & 63, ct = o >> 6;
        const int cl = ct * 16 + (lane & 15);
        const int r0 = (lane >> 4) * 8;
        us8 v;
#pragma unroll
        for (int j = 0; j < 8; ++j) v[j] = rtn(lds[r0 + j][cl]);
        wpk[(size_t)g * 1024 + o] = v;
    }

    // wT: (K, VEC) f32 transpose for coalesced per-col reads in recheck
#pragma unroll
    for (int rr = 0; rr < 8; ++rr) {
        f32x4 v = {lds[rr * 4 + 0][t], lds[rr * 4 + 1][t], lds[rr * 4 + 2][t], lds[rr * 4 + 3][t]};
        *(f32x4*)&wT[(size_t)(gx * 256 + t) * VEC + ks * 32 + rr * 4] = v;
    }

    if (g < 8) cc[g * 256 + t] = 0;
    if (g == 8 && t == 0) cc[2048] = 0;
}

// ---- main: 128x256 single-bf16 MFMA distance GEMM, top-2 per row per slot ----
// 2048 blocks x 512 thr; 2 blocks/CU (48KB LDS, <=128 VGPR -- NO spill).
// Counted-vmcnt pipeline: next-tile staging stays in flight across barriers.
__launch_bounds__(512, 4)
__global__ void k_gemm(const float* __restrict__ x, const us8* __restrict__ wpk,
                       const float* __restrict__ w2p,
                       u64* __restrict__ keysA, u64* __restrict__ keysB) {
    __shared__ us8 a_lds[2][512];    // 128 rows x 32k bf16, 8KB/buf
    __shared__ us8 b_lds[2][1024];   // 256 cols x 32k bf16, 16KB/buf

    const int blk = blockIdx.x;
    // XCD-chunked bijection (2048 % 8 == 0): XCD c owns gy [c*64, c*64+64),
    // the 4 gx of each gy adjacent -> A-tile L2 reuse.
    const int gy = (blk & 7) * 64 + ((blk >> 3) >> 2);
    const int gx = (blk >> 3) & 3;
    const int t = threadIdx.x;
    const int lane = t & 63;
    const int wv = t >> 6;
    const int wm = wv >> 2;      // 0..1 (64 rows)
    const int wn = wv & 3;       // 0..3 (64 cols)

    const us8* bsrc = wpk + (size_t)gx * (NKT * 1024);

    // A staging: thread t owns granule t: slab=t>>6, al=t&63
    const int al = t & 63;
    const float* xp = x + (size_t)(gy * 128 + (t >> 6) * 16 + (al & 15)) * VEC + (al >> 4) * 8;
    f32x4 av0, av1;
    auto aload = [&](int kt) {
        const float* p = xp + kt * 32;
        av0 = *(const f32x4*)p;
        av1 = *(const f32x4*)(p + 4);
    };
    auto awrite = [&](int buf) {
        us8 h;
#pragma unroll
        for (int j = 0; j < 4; ++j) { h[j] = rtn(av0[j]); h[4 + j] = rtn(av1[j]); }
        a_lds[buf][t] = h;
    };
    auto bstage = [&](int buf, int kt) {
        const us8* sb = bsrc + (size_t)kt * 1024;
        gl16(sb + t, &b_lds[buf][t]);
        gl16(sb + 512 + t, &b_lds[buf][512 + t]);
    };

    f32x4 acc[4][4];
#pragma unroll
    for (int i = 0; i < 4; ++i)
#pragma unroll
        for (int j = 0; j < 4; ++j) acc[i][j] = (f32x4){0.f, 0.f, 0.f, 0.f};

    // prologue: tile 0. aload->awrite (compiler inserts its own precise vmcnt
    // for the av dependency); gl16(0) stays in flight; lgkm drained before B1.
    aload(0);
    bstage(0, 0);
    awrite(0);
    asm volatile("s_waitcnt lgkmcnt(0)" ::: "memory");

    for (int tk = 0; tk < NKT; ++tk) {
        const int buf = tk & 1;
        const bool nx = (tk + 1 < NKT);
        if (nx) {
            aload(tk + 1);              // 2 vmem (vgpr dest)
            bstage(buf ^ 1, tk + 1);    // 2 vmem (lds dest)
            // drain gl16(tk) [oldest]; leave aload(tk+1)+gl16(tk+1) in flight
            asm volatile("s_waitcnt vmcnt(4)" ::: "memory");
        } else {
            asm volatile("s_waitcnt vmcnt(0)" ::: "memory");
        }
        __builtin_amdgcn_s_barrier();   // B1: all threads' tile-tk staging visible

        bf16x8 bh[4];
#pragma unroll
        for (int ct = 0; ct < 4; ++ct)
            bh[ct] = __builtin_bit_cast(bf16x8, b_lds[buf][(wn * 4 + ct) * 64 + lane]);
#pragma unroll
        for (int rt = 0; rt < 4; ++rt) {
            bf16x8 ah = __builtin_bit_cast(bf16x8, a_lds[buf][(wm * 4 + rt) * 64 + lane]);
#pragma unroll
            for (int ct = 0; ct < 4; ++ct)
                acc[rt][ct] = __builtin_amdgcn_mfma_f32_16x16x32_bf16(ah, bh[ct], acc[rt][ct], 0, 0, 0);
        }

        if (nx) awrite(buf ^ 1);        // compiler inserts vmcnt for av regs
        asm volatile("s_waitcnt lgkmcnt(0)" ::: "memory");
        __builtin_amdgcn_s_barrier();   // B2: awrite visible; WAR guard
    }

    // epilogue: dist = w2 - 2*dot; per-row TOP-2 over this wave's 64 cols;
    // plain store to slot (gx*4+wn) -- no atomics, deterministic.
    const int col_base = gx * 256 + wn * 64;
    float w2c[4];
#pragma unroll
    for (int ct = 0; ct < 4; ++ct) {
        const int col = col_base + ct * 16 + (lane & 15);
        float s = 0.f;
#pragma unroll
        for (int p = 0; p < 16; ++p) s += w2p[p * K + col];
        w2c[ct] = s;
    }
    const int slot = gx * 4 + wn;

#pragma unroll
    for (int rt = 0; rt < 4; ++rt) {
#pragma unroll
        for (int reg = 0; reg < 4; ++reg) {
            u64 k1 = ~0ull, k2 = ~0ull;
#pragma unroll
            for (int ct = 0; ct < 4; ++ct) {
                float dist = w2c[ct] - 2.0f * acc[rt][ct][reg];
                uint su = __float_as_uint(dist);
                su = (su & 0x80000000u) ? ~su : (su | 0x80000000u);
                const u64 key = ((u64)su << 32) | (uint)(col_base + ct * 16 + (lane & 15));
                if (key < k1) { k2 = k1; k1 = key; }
                else if (key < k2) { k2 = key; }
            }
#pragma unroll
            for (int m = 1; m < 16; m <<= 1) {
                u64 o1 = __shfl_xor((unsigned long long)k1, m);
                u64 o2 = __shfl_xor((unsigned long long)k2, m);
                u64 lo = k1 < o1 ? k1 : o1;
                u64 hi = k1 < o1 ? o1 : k1;
                u64 mn2 = k2 < o2 ? k2 : o2;
                k1 = lo;
                k2 = hi < mn2 ? hi : mn2;
            }
            if ((lane & 15) == 0) {
                const int row = gy * 128 + wm * 64 + rt * 16 + (lane >> 4) * 4 + reg;
                keysA[(size_t)slot * BATCH + row] = k1;
                keysB[(size_t)slot * BATCH + row] = k2;
            }
        }
    }
}

// ---- verify: merge 16 slots/row -> global top-2; margin test; hist; list ----
__global__ void k_verify(const u64* __restrict__ keysA, const u64* __restrict__ keysB,
                         int* __restrict__ am, int* __restrict__ counts,
                         u64* __restrict__ list, int* __restrict__ listcnt,
                         float* __restrict__ esum) {
    const int r = blockIdx.x * 256 + threadIdx.x;
    f32x4 z = {0.f, 0.f, 0.f, 0.f};
    ((f32x4*)esum)[r * 2] = z;
    ((f32x4*)esum)[r * 2 + 1] = z;

    u64 m1 = ~0ull, s = ~0ull;
    int i1 = 0;
#pragma unroll
    for (int i = 0; i < 16; ++i) {
        u64 a = keysA[(size_t)i * BATCH + r];
        if (a < m1) { s = m1; m1 = a; i1 = i; }
        else if (a < s) s = a;
    }
    u64 b = keysB[(size_t)i1 * BATCH + r];
    u64 m2 = s < b ? s : b;

    const float d1 = dec_key((uint)(m1 >> 32));
    const float d2 = dec_key((uint)(m2 >> 32));
    const int c1 = (int)(uint)m1 & 1023;
    const int c2 = (int)(uint)m2 & 1023;

    if (d2 - d1 > MARGIN) {
        am[r] = c1;
        atomicAdd(&counts[c1], 1);
    } else {
        int p = atomicAdd(listcnt, 1);
        list[p] = ((u64)(uint)r << 32) | ((uint)c1 << 10) | (uint)c2;
    }
}

// ---- recheck: exact f32 distance for the 2 candidates of marginal rows ----
__launch_bounds__(256)
__global__ void k_recheck(const float* __restrict__ x, const float* __restrict__ wT,
                          const float* __restrict__ w2p, const u64* __restrict__ list,
                          const int* __restrict__ listcnt, int* __restrict__ am,
                          int* __restrict__ counts) {
    const int gwid = (blockIdx.x * 256 + threadIdx.x) >> 6;   // 1024 waves
    const int lane = threadIdx.x & 63;
    const int n = *listcnt;
    for (int idx = gwid; idx < n; idx += 1024) {
        const u64 e = list[idx];
        const int r = (int)(e >> 32);
        const int c1 = (int)((e >> 10) & 1023);
        const int c2 = (int)(e & 1023);
        const f32x4 x0 = *(const f32x4*)&x[(size_t)r * VEC + lane * 8];
        const f32x4 x1 = *(const f32x4*)&x[(size_t)r * VEC + lane * 8 + 4];
        float d[2];
        const int cc2[2] = {c1, c2};
#pragma unroll
        for (int j = 0; j < 2; ++j) {
            const int c = cc2[j];
            const f32x4 w0 = *(const f32x4*)&wT[(size_t)c * VEC + lane * 8];
            const f32x4 w1 = *(const f32x4*)&wT[(size_t)c * VEC + lane * 8 + 4];
            float p = x0[0] * w0[0] + x0[1] * w0[1] + x0[2] * w0[2] + x0[3] * w0[3]
                    + x1[0] * w1[0] + x1[1] * w1[1] + x1[2] * w1[2] + x1[3] * w1[3];
#pragma unroll
            for (int m = 1; m < 64; m <<= 1) p += __shfl_xor(p, m);
            float w2 = 0.f;
#pragma unroll
            for (int q = 0; q < 16; ++q) w2 += w2p[q * K + c];
            d[j] = w2 - 2.0f * p;
        }
        const int win = (d[0] < d[1] || (d[0] == d[1] && c1 < c2)) ? c1 : c2;
        if (lane == 0) {
            am[r] = win;
            atomicAdd(&counts[win], 1);
        }
    }
}

// ---- scan of counts -> offsets; EMA cluster sizes -> cs (wave-shuffle) ----
__global__ void k_scan(const int* __restrict__ counts,
                       const float* __restrict__ cluster_size,
                       int* __restrict__ offsets, float* __restrict__ cs) {
    __shared__ int wsum[16];
    __shared__ float fw[16];
    const int t = threadIdx.x;           // 0..1023
    const int lane = t & 63, wid = t >> 6;
    const int c = counts[t];

    int s = c;
#pragma unroll
    for (int d = 1; d < 64; d <<= 1) {
        int o = __shfl_up(s, d);
        if (lane >= d) s += o;
    }
    float ncs = GAMMA * cluster_size[t] + (1.0f - GAMMA) * ((c == 0) ? 1.0f : (float)c);
    float fs = ncs;
#pragma unroll
    for (int d = 32; d > 0; d >>= 1) fs += __shfl_xor(fs, d);

    if (lane == 63) wsum[wid] = s;
    if (lane == 0) fw[wid] = fs;
    __syncthreads();
    if (wid == 0 && lane < 16) {
        int v = wsum[lane];
#pragma unroll
        for (int d = 1; d < 16; d <<= 1) {
            int o = __shfl_up(v, d);
            if (lane >= d) v += o;
        }
        wsum[lane] = v;
    }
    __syncthreads();
    const int base = wid ? wsum[wid - 1] : 0;
    offsets[t] = base + s - c;

    float n = 0.f;
#pragma unroll
    for (int i = 0; i < 16; ++i) n += fw[i];
    cs[t] = (ncs + EPS) / (n + (float)K * EPS) * n;
}

// ---- counting-sort scatter ----
__global__ void k_scatter(const int* __restrict__ am, const int* __restrict__ offsets,
                          int* __restrict__ cursor, int* __restrict__ sorted,
                          int* __restrict__ sortedk) {
    const int b = blockIdx.x * blockDim.x + threadIdx.x;
    const int k = am[b];
    const int pos = atomicAdd(&cursor[k], 1);
    sorted[offsets[k] + pos] = b;
    sortedk[offsets[k] + pos] = k;
}

// ---- balanced segmented reduction: 64 sorted rows per block ----
__launch_bounds__(512)
__global__ void k_segred(const float* __restrict__ x, const int* __restrict__ sorted,
                         const int* __restrict__ sortedk, float* __restrict__ esum) {
    __shared__ int srow[SEG];
    __shared__ int skid[SEG];
    const int b = blockIdx.x;
    const int t = threadIdx.x;
    if (t < SEG) {
        srow[t] = sorted[b * SEG + t];
        skid[t] = sortedk[b * SEG + t];
    }
    __syncthreads();

    float a = 0.f;
    int cur = skid[0];
#pragma unroll 8
    for (int i = 0; i < SEG; ++i) {
        const int k = skid[i];
        if (k != cur) {
            atomicAdd(&esum[(size_t)cur * VEC + t], a);
            a = 0.f;
            cur = k;
        }
        a += x[(size_t)srow[i] * VEC + t];
    }
    atomicAdd(&esum[(size_t)cur * VEC + t], a);
}

// ---- finalize: transpose esum (K,VEC)->(VEC,K), EMA + normalize ----
__launch_bounds__(256)
__global__ void k_finalize(const float* __restrict__ esum, const float* __restrict__ embed_avg,
                           const float* __restrict__ cs, float* __restrict__ out) {
    __shared__ float tile[64][65];
    const int k0 = blockIdx.x * 64;
    const int v0 = blockIdx.y * 64;
    const int c = threadIdx.x & 63;
    const int r0 = threadIdx.x >> 6;
#pragma unroll
    for (int j = 0; j < 16; ++j) {
        const int r = r0 + j * 4;
        tile[r][c] = esum[(size_t)(k0 + r) * VEC + v0 + c];
    }
    __syncthreads();
    const float csk = cs[k0 + c];
#pragma unroll
    for (int j = 0; j < 16; ++j) {
        const int r = r0 + j * 4;
        const size_t o = (size_t)(v0 + r) * K + k0 + c;
        out[o] = (GAMMA * embed_avg[o] + (1.0f - GAMMA) * tile[c][r]) / csk;
    }
}

extern "C" void kernel_launch(void* const* d_in, const int* in_sizes, int n_in,
                              void* d_out, int out_size, void* d_ws, size_t ws_size,
                              hipStream_t stream) {
    const float* x            = (const float*)d_in[0];   // (BATCH, VEC)
    const float* w            = (const float*)d_in[1];   // (VEC, K)
    const float* cluster_size = (const float*)d_in[2];   // (K,)
    const float* embed_avg    = (const float*)d_in[3];   // (VEC, K)
    float* out = (float*)d_out;                          // (VEC, K)

    // ws layout (~23 MB)
    u64*   keysA   = (u64*)d_ws;                          // 16 x BATCH
    u64*   keysB   = keysA + (size_t)16 * BATCH;          // 16 x BATCH
    int*   am      = (int*)(keysB + (size_t)16 * BATCH);  // BATCH
    u64*   list    = (u64*)(am + BATCH);                  // BATCH
    float* w2p     = (float*)(list + BATCH);              // 16 x K
    float* cs      = w2p + 16 * K;                        // K
    int*   cc      = (int*)(cs + K);                      // counts K | cursor K | listcnt (+pad)
    int*   counts  = cc;
    int*   cursor  = cc + K;
    int*   listcnt = cc + 2 * K;
    int*   offsets = cc + 2 * K + 64;                     // K
    int*   sorted  = offsets + K;                         // BATCH
    int*   sortedk = sorted + BATCH;                      // BATCH
    float* esum    = (float*)(sortedk + BATCH);           // (K, VEC), 2 MB
    us8*   wpk     = (us8*)(esum + (size_t)K * VEC);      // 1 MB
    float* wT      = (float*)(wpk + (size_t)64 * 1024);   // (K, VEC), 2 MB

    k_pack_w<<<64, 256, 0, stream>>>(w, wpk, wT, w2p, cc);
    k_gemm<<<2048, 512, 0, stream>>>(x, wpk, w2p, keysA, keysB);
    k_verify<<<BATCH / 256, 256, 0, stream>>>(keysA, keysB, am, counts, list, listcnt, esum);
    k_recheck<<<256, 256, 0, stream>>>(x, wT, w2p, list, listcnt, am, counts);
    k_scan<<<1, K, 0, stream>>>(counts, cluster_size, offsets, cs);
    k_scatter<<<BATCH / 256, 256, 0, stream>>>(am, offsets, cursor, sorted, sortedk);
    k_segred<<<BATCH / SEG, 512, 0, stream>>>(x, sorted, sortedk, esum);
    k_finalize<<<dim3(K / 64, VEC / 64), 256, 0, stream>>>(esum, embed_avg, cs, out);
}